// Round 9
// baseline (604.875 us; speedup 1.0000x reference)
//
#include <hip/hip_runtime.h>
#include <math.h>

// Problem constants (from reference)
#define HH    2560   // hidden units
#define ESZ   2048   // excitatory units (first ESZ rows/cols)
#define BB    64     // batch
#define TT    32     // time steps
#define INSZ  128    // input size
#define PITCH 1664   // packed-W pitch in floats; row stride bytes = 6656 (0x1a00)
constexpr float ALPHA_C = 0.2f;   // dt_x / tau_x = 0.02/0.1

typedef __attribute__((ext_vector_type(16))) float sf16;  // 16 SGPRs (s_load_dwordx16)

__device__ __forceinline__ float retanh_f(float v) { return tanhf(fmaxf(v, 0.f)); }

// Every row of area `a` (E and I alike) has the identical sparse column set:
// E-cols of areas [a-1..a+1] + I-cols of area a (+ input cols for area 0).
__device__ __forceinline__ void area_params(int area, int& e_lo, int& n_e,
                                            int& i_lo, int& n_rec, int& n_tot) {
    e_lo = (area > 0 ? area - 1 : 0) << 9;
    int e_hi = ((area < 3 ? area + 1 : 3) + 1) << 9;
    n_e = e_hi - e_lo;               // 1024 or 1536
    i_lo = ESZ + (area << 7);
    n_rec = n_e + 128;               // 1152 or 1664
    n_tot = n_rec + (area == 0 ? INSZ : 0);   // 1280 / 1664 / 1664 / 1152
}

// area-row index (0..639; 512 E rows then 128 I rows) -> global row h
__device__ __forceinline__ int row_h(int area, int idx) {
    return (idx < 512) ? ((area << 9) + idx) : (ESZ + (area << 7) + (idx - 512));
}

// global row h -> packed row index r (area-major ordering)
__device__ __forceinline__ int pack_r(int h) {
    return (h < ESZ) ? ((h >> 9) * 640 + (h & 511))
                     : (((h - ESZ) >> 7) * 640 + 512 + ((h - ESZ) & 127));
}

// ---- Pack W once: Wp[r][p] = masked/signed/diag-zeroed |W| in dense sparse layout,
//      with W_in columns appended for area-0 rows. grid (13, 2560), block 128.
__global__ __launch_bounds__(128) void pack_w(const float* __restrict__ Wrec,
                                              const float* __restrict__ Win,
                                              float* __restrict__ Wp) {
    const int p = blockIdx.x * 128 + threadIdx.x;   // < PITCH
    const int r = blockIdx.y;                        // < HH
    const int area = r / 640, idx = r % 640;
    int e_lo, n_e, i_lo, n_rec, n_tot;
    area_params(area, e_lo, n_e, i_lo, n_rec, n_tot);
    const int h = row_h(area, idx);
    float w = 0.f;
    if (p < n_e) {
        int c = e_lo + p;
        w = (c == h) ? 0.f : fabsf(Wrec[(size_t)h * HH + c]);        // E col: +|w|
    } else if (p < n_rec) {
        int c = i_lo + (p - n_e);
        w = (c == h) ? 0.f : -fabsf(Wrec[(size_t)h * HH + c]);       // I col: -|w|
    } else if (p < n_tot) {
        w = fabsf(Win[(size_t)h * INSZ + (p - n_rec)]);              // input col (+1 mask)
    }
    Wp[(size_t)r * PITCH + p] = w;
}

// ---- Init: stateT[r][b] (packed-row order), actA = retanh(state0) in paired layout
__global__ __launch_bounds__(256) void init_state2(const float* __restrict__ state0,
                                                   float* __restrict__ stateT,
                                                   float* __restrict__ act0) {
    int idx = blockIdx.x * 256 + threadIdx.x;   // < BB*HH
    int b = idx / HH, h = idx - b * HH;
    float s = state0[idx];
    stateT[pack_r(h) * BB + b] = s;
    act0[((h >> 1) << 7) + b * 2 + (h & 1)] = retanh_f(s);
}

// Issue 5 s_load_dwordx16 (one per row, 64 B each = 16 cols), row stride 0x1a00.
#define ISSUE16(Q0,Q1,Q2,Q3,Q4,BASE)                                      \
    asm volatile(                                                          \
        "s_load_dwordx16 %0, %5, 0x0\n\t"                                  \
        "s_load_dwordx16 %1, %5, 0x1a00\n\t"                               \
        "s_load_dwordx16 %2, %5, 0x3400\n\t"                               \
        "s_load_dwordx16 %3, %5, 0x4e00\n\t"                               \
        "s_load_dwordx16 %4, %5, 0x6800"                                   \
        : "=&s"(Q0), "=&s"(Q1), "=&s"(Q2), "=&s"(Q3), "=&s"(Q4)            \
        : "s"(BASE))

// Drain scalar returns; tie values so uses can't be hoisted above the wait.
#define WAIT16(Q0,Q1,Q2,Q3,Q4)                                            \
    asm volatile("s_waitcnt lgkmcnt(0)"                                    \
        : "+s"(Q0), "+s"(Q1), "+s"(Q2), "+s"(Q3), "+s"(Q4))

// Row J over 16 cols: W[i] = col i, AV[k] = (col 2k, col 2k+1).
#define FMA16(J, W, AV)                                                       \
    acc[J].x = fmaf(W[0],  AV[0].x, acc[J].x);                                \
    acc[J].y = fmaf(W[1],  AV[0].y, acc[J].y);                                \
    acc[J].x = fmaf(W[2],  AV[1].x, acc[J].x);                                \
    acc[J].y = fmaf(W[3],  AV[1].y, acc[J].y);                                \
    acc[J].x = fmaf(W[4],  AV[2].x, acc[J].x);                                \
    acc[J].y = fmaf(W[5],  AV[2].y, acc[J].y);                                \
    acc[J].x = fmaf(W[6],  AV[3].x, acc[J].x);                                \
    acc[J].y = fmaf(W[7],  AV[3].y, acc[J].y);                                \
    acc[J].x = fmaf(W[8],  AV[4].x, acc[J].x);                                \
    acc[J].y = fmaf(W[9],  AV[4].y, acc[J].y);                                \
    acc[J].x = fmaf(W[10], AV[5].x, acc[J].x);                                \
    acc[J].y = fmaf(W[11], AV[5].y, acc[J].y);                                \
    acc[J].x = fmaf(W[12], AV[6].x, acc[J].x);                                \
    acc[J].y = fmaf(W[13], AV[6].y, acc[J].y);                                \
    acc[J].x = fmaf(W[14], AV[7].x, acc[J].x);                                \
    acc[J].y = fmaf(W[15], AV[7].y, acc[J].y);

// ---- One RNN step. 512 blocks x 512 thr (8 waves) -> 2 blocks/CU.
// Block = 5 rows; chunk = 16 cols (one 64-B line) via 5 s_load_dwordx16;
// single-buffered (scalar path is throughput-bound, not latency-bound:
// R5->R6 pipelining was neutral). launch_bounds(512,4): SGPR-safe (R7 post-mortem).
__global__ __launch_bounds__(512, 4) void step7(
    const float* __restrict__ Wp,      // packed [HH][PITCH]
    const float* __restrict__ brec,
    const float* __restrict__ x_t,     // [BB][INSZ]
    const float* __restrict__ actIn,   // paired [h/2][BB][2]
    float* __restrict__ actOut,
    float* __restrict__ stateT,        // [r][BB]
    float* __restrict__ out_t)         // [BB][HH]
{
    __shared__ float part[8 * 340];    // [wave][j*68 + lane], 10.9 KB
    const int tid = threadIdx.x, lane = tid & 63, wv = tid >> 6;   // wv 0..7
    // bid%8 = XCD; area=(bid>>1)&3 pins each area to an XCD pair.
    // (area, (bid>>3)*2+(bid&1)) is bijective over 4 x 128 row-groups.
    const int bid  = blockIdx.x;
    const int area = (bid >> 1) & 3;
    const int rb   = ((bid >> 3) * 2 + (bid & 1)) * 5;
    int e_lo, n_e, i_lo, n_rec, n_tot;
    area_params(area, e_lo, n_e, i_lo, n_rec, n_tot);
    const int r0 = area * 640 + rb;
    const int C16 = n_tot >> 4;        // 16-col chunks: 80/104/104/72 (all %8==0)

    float2 acc[5];
#pragma unroll
    for (int j = 0; j < 5; j++) acc[j] = make_float2(0.f, 0.f);

    // act loader for a 16-col chunk starting at packed col p0 (16-aligned;
    // chunks never straddle n_e or n_rec: both are multiples of 16)
    auto load_act = [&](int p0, float2* av) {
        if (p0 < n_rec) {
            const int cb = (p0 < n_e) ? (e_lo + p0) : (i_lo + (p0 - n_e));
            const float* ap = actIn + ((cb >> 1) << 7) + (lane << 1);
#pragma unroll
            for (int i = 0; i < 8; i++) av[i] = *(const float2*)(ap + (i << 7));
        } else {
            const int k0 = p0 - n_rec;
#pragma unroll
            for (int q = 0; q < 4; q++) {
                float4 v = *(const float4*)(x_t + lane * INSZ + k0 + 4 * q);
                av[2 * q]     = make_float2(fmaxf(v.x, 0.f), fmaxf(v.y, 0.f));
                av[2 * q + 1] = make_float2(fmaxf(v.z, 0.f), fmaxf(v.w, 0.f));
            }
        }
    };

    // Wave-uniform W base; chunk c starts at byte c*64 within the packed row
    // (rows are 6656 B = 104 cache lines, so every chunk is 64-B aligned).
    const float* wb = Wp + (size_t)r0 * PITCH
                         + ((size_t)__builtin_amdgcn_readfirstlane(wv) << 4);
    sf16 Q0, Q1, Q2, Q3, Q4;
    float2 av[8];

    for (int c = wv; c < C16; c += 8) {
        ISSUE16(Q0, Q1, Q2, Q3, Q4, wb);
        load_act(c << 4, av);
        WAIT16(Q0, Q1, Q2, Q3, Q4);
        FMA16(0, Q0, av)
        FMA16(1, Q1, av)
        FMA16(2, Q2, av)
        FMA16(3, Q3, av)
        FMA16(4, Q4, av)
        wb += 128;   // 8 chunks * 16 floats
    }

#pragma unroll
    for (int j = 0; j < 5; j++)
        part[wv * 340 + j * 68 + lane] = acc[j].x + acc[j].y;
    __syncthreads();

    // Epilogue: 320 (row,batch) items; j = tid&7 (<5), b = tid>>3 keeps out_t
    // writes h-consecutive per 8 lanes.
    {
        const int j = tid & 7, b = tid >> 3;
        if (j < 5) {
            const int h = row_h(area, rb + j);
            float s = 0.f;
#pragma unroll
            for (int w8 = 0; w8 < 8; w8++) s += part[w8 * 340 + j * 68 + b];
            const int r = r0 + j;
            float st = stateT[r * BB + b];
            float ns = st * (1.f - ALPHA_C) + ALPHA_C * (s + brec[h]);
            stateT[r * BB + b] = ns;
            float o = retanh_f(ns);
            out_t[(size_t)b * HH + h] = o;
            actOut[((h >> 1) << 7) + b * 2 + (h & 1)] = o;
        }
    }
}

// ---- Fallback (no workspace): stream raw W, masked on the fly (R3-style, 256 blocks).
__global__ __launch_bounds__(1024, 4) void step_raw(
    const float* __restrict__ W, const float* __restrict__ Win,
    const float* __restrict__ brec, const float* __restrict__ x_t,
    const float* __restrict__ actIn, float* __restrict__ actOut,
    float* __restrict__ stateT, float* __restrict__ out_t)
{
    __shared__ float part[16 * 680];
    const int tid = threadIdx.x, lane = tid & 63, wv = tid >> 6;
    const int area = blockIdx.x >> 6;
    const int rb = (blockIdx.x & 63) * 10;
    int e_lo, n_e, i_lo, n_rec, n_tot;
    area_params(area, e_lo, n_e, i_lo, n_rec, n_tot);
    const int r0 = area * 640 + rb;
    const int C = n_tot >> 4;

    float2 acc[10];
#pragma unroll
    for (int j = 0; j < 10; j++) acc[j] = make_float2(0.f, 0.f);

    for (int c = wv; c < C; c += 16) {
        const int p0 = c << 4;
        float2 av[8];
        int cbase;
        if (p0 < n_rec) {
            cbase = (p0 < n_e) ? (e_lo + p0) : (i_lo + (p0 - n_e));
            const float* ap = actIn + ((cbase >> 1) << 7) + lane * 2;
#pragma unroll
            for (int i = 0; i < 8; i++) av[i] = *(const float2*)(ap + (i << 7));
        } else {
            cbase = -1;
            const int k0 = p0 - n_rec;
            const float4* xp = (const float4*)(x_t + lane * INSZ + k0);
#pragma unroll
            for (int q = 0; q < 4; q++) {
                float4 v = xp[q];
                av[2 * q]     = make_float2(fmaxf(v.x, 0.f), fmaxf(v.y, 0.f));
                av[2 * q + 1] = make_float2(fmaxf(v.z, 0.f), fmaxf(v.w, 0.f));
            }
        }
#pragma unroll
        for (int j = 0; j < 10; j++) {
            const int h = row_h(area, rb + j);
            const float sgn = (cbase >= 0 && p0 >= n_e) ? -1.f : 1.f;
            const float* wr = (cbase >= 0) ? (W + (size_t)h * HH + cbase)
                                           : (Win + (size_t)h * INSZ + (p0 - n_rec));
#pragma unroll
            for (int i = 0; i < 8; i++) {
                float wx = sgn * fabsf(wr[2 * i]);
                float wy = sgn * fabsf(wr[2 * i + 1]);
                acc[j].x = fmaf(wx, av[i].x, acc[j].x);
                acc[j].y = fmaf(wy, av[i].y, acc[j].y);
            }
        }
    }

#pragma unroll
    for (int j = 0; j < 10; j++)
        part[wv * 680 + j * 68 + lane] = acc[j].x + acc[j].y;
    __syncthreads();

    int j = -1, b = 0;
    if (tid < 512)      { b = tid >> 3;      j = tid & 7; }
    else if (tid < 640) { int u = tid - 512; b = u >> 1;  j = 8 + (u & 1); }
    if (j >= 0) {
        const int h = row_h(area, rb + j);
        float s = 0.f;
#pragma unroll
        for (int w16 = 0; w16 < 16; w16++) s += part[w16 * 680 + j * 68 + b];
        {   // diag was included above; subtract it (mask has zero diag)
            float sgn = (h < ESZ) ? 1.f : -1.f;
            float ah = actIn[((h >> 1) << 7) + b * 2 + (h & 1)];
            s -= sgn * fabsf(W[(size_t)h * HH + h]) * ah;
        }
        const int r = r0 + j;
        float st = stateT[r * BB + b];
        float ns = st * (1.f - ALPHA_C) + ALPHA_C * (s + brec[h]);
        stateT[r * BB + b] = ns;
        float o = retanh_f(ns);
        out_t[(size_t)b * HH + h] = o;
        actOut[((h >> 1) << 7) + b * 2 + (h & 1)] = o;
    }
}

extern "C" void kernel_launch(void* const* d_in, const int* in_sizes, int n_in,
                              void* d_out, int out_size, void* d_ws, size_t ws_size,
                              hipStream_t stream) {
    const float* x      = (const float*)d_in[0];   // [TT][BB][INSZ]
    const float* W_in   = (const float*)d_in[1];   // [HH][INSZ]
    const float* W_rec  = (const float*)d_in[2];   // [HH][HH]
    const float* b_rec  = (const float*)d_in[3];   // [HH]
    const float* state0 = (const float*)d_in[4];   // [BB][HH]
    float* out = (float*)d_out;                    // [TT][BB][HH]
    float* ws = (float*)d_ws;

    const size_t packElems = (size_t)HH * PITCH;
    const size_t bufElems  = (size_t)HH * BB;
    const bool pre = ws_size >= (packElems + 3 * bufElems) * sizeof(float);

    float* Wp     = ws;
    float* stateT = pre ? (ws + packElems) : ws;
    float* actA   = stateT + bufElems;
    float* actB   = actA + bufElems;

    if (pre) pack_w<<<dim3(13, HH), 128, 0, stream>>>(W_rec, W_in, Wp);
    init_state2<<<(BB * HH) / 256, 256, 0, stream>>>(state0, stateT, actA);

    for (int t = 0; t < TT; t++) {
        const float* ai = (t & 1) ? actB : actA;
        float* ao       = (t & 1) ? actA : actB;
        const float* xt = x + (size_t)t * BB * INSZ;
        float* ot       = out + (size_t)t * BB * HH;
        if (pre)
            step7<<<512, 512, 0, stream>>>(Wp, b_rec, xt, ai, ao, stateT, ot);
        else
            step_raw<<<256, 1024, 0, stream>>>(W_rec, W_in, b_rec, xt, ai, ao, stateT, ot);
    }
}

// Round 10
// 301.338 us; speedup vs baseline: 2.0073x; 2.0073x over previous
//
#include <hip/hip_runtime.h>
#include <math.h>

// Problem constants (from reference)
#define HH   2560
#define ESZ  2048
#define BB   64
#define TT   32
#define INSZ 128
constexpr float ALPHA_C = 0.2f;   // dt_x / tau_x

typedef unsigned short ushort_t;
typedef __attribute__((ext_vector_type(8))) unsigned short u16x8;  // 8 bf16 = 4 VGPRs
typedef __attribute__((ext_vector_type(4))) float f32x4;           // MFMA acc

__device__ __forceinline__ float retanh_f(float v) { return tanhf(fmaxf(v, 0.f)); }
__device__ __forceinline__ ushort_t f2bf(float f) {   // RNE float->bf16
    unsigned u = __float_as_uint(f);
    return (ushort_t)((u + 0x7fffu + ((u >> 16) & 1u)) >> 16);
}

// Area geometry (kron structure). Rows of area a (E and I) share one sparse col set:
// E-cols of areas [a-1..a+1] (n_e), then I-cols of area a (128), then x-cols (area0).
__device__ __forceinline__ int area_ne(int a)  { return (a == 1 || a == 2) ? 1536 : 1024; }
__device__ __forceinline__ int area_elo(int a) { return (a > 0 ? a - 1 : 0) << 9; }
__device__ __forceinline__ int area_kc(int a)  { return (a == 0) ? 40 : ((a == 3) ? 36 : 52); }
// KC*32 == n_tot exactly: 1280/1664/1664/1152.

// ============ fragment-layout packers (once per launch) ============
// WF[(mt*52+kc)*512 + lane*8 + j] = bf16 A-fragment: W row m = mt*16+(lane&15),
// packed col k = kc*32 + (lane>>4)*8 + j  (masked/signed/diag-zeroed |W|, Win appended)
__global__ __launch_bounds__(256) void wf_pack(const float* __restrict__ Wrec,
                                               const float* __restrict__ Win,
                                               ushort_t* __restrict__ WF) {
    int idx = blockIdx.x * 256 + threadIdx.x;   // < 160*52*512
    int j = idx & 7, l = (idx >> 3) & 63;
    int t = idx >> 9;                 // mt*52 + kc
    int kc = t % 52, mt = t / 52;
    int area = mt / 40, local = mt - area * 40;
    int ridx = local * 16 + (l & 15);             // within-area packed row 0..639
    int h = (ridx < 512) ? ((area << 9) + ridx) : (ESZ + (area << 7) + (ridx - 512));
    int p = kc * 32 + ((l >> 4) << 3) + j;
    int ne = area_ne(area), elo = area_elo(area);
    int nrec = ne + 128;
    int ntot = nrec + (area == 0 ? 128 : 0);
    float w = 0.f;
    if (p < ne)        { int c = elo + p;                      w = (c == h) ? 0.f :  fabsf(Wrec[(size_t)h * HH + c]); }
    else if (p < nrec) { int c = ESZ + (area << 7) + (p - ne); w = (c == h) ? 0.f : -fabsf(Wrec[(size_t)h * HH + c]); }
    else if (p < ntot) { w = fabsf(Win[(size_t)h * INSZ + (p - nrec)]); }
    WF[idx] = f2bf(w);
}

// xF[t*8192 + kc*2048 + nt*512 + lane*8 + j] = bf16 B-fragment of relu(x_t) for
// area0 x-cols: b = nt*16+(lane&15), k_in = kc*32+(lane>>4)*8+j
__global__ __launch_bounds__(256) void xf_pack(const float* __restrict__ x,
                                               ushort_t* __restrict__ xF) {
    int idx = blockIdx.x * 256 + threadIdx.x;   // < 32*4*4*512
    int j = idx & 7, l = (idx >> 3) & 63;
    int nt = (idx >> 9) & 3, kc = (idx >> 11) & 3, t = idx >> 13;
    int b = nt * 16 + (l & 15);
    int k = kc * 32 + ((l >> 4) << 3) + j;
    xF[idx] = f2bf(fmaxf(x[((size_t)t * BB + b) * INSZ + k], 0.f));
}

// scatter one act value into B-fragment slots of every area whose col-space has h
__device__ __forceinline__ void act_store(ushort_t* actF, int a, int p, int b, ushort_t v) {
    int kc = p >> 5, kk = p & 31;
    int lane = ((kk >> 3) << 4) + (b & 15);
    actF[(((a * 52 + kc) << 2) + (b >> 4)) * 512 + lane * 8 + (kk & 7)] = v;
}
__device__ __forceinline__ void scatter_act(ushort_t* actF, int h, int b, ushort_t v) {
    if (h < ESZ) {
        int ae = h >> 9;
        int alo = ae > 0 ? ae - 1 : 0, ahi = ae < 3 ? ae + 1 : 3;
        for (int a = alo; a <= ahi; a++) act_store(actF, a, h - area_elo(a), b, v);
    } else {
        int ai = (h - ESZ) >> 7;
        act_store(actF, ai, area_ne(ai) + (h - (ESZ + (ai << 7))), b, v);
    }
}

// state0 -> stateT (packed-row fp32) + initial act fragments
__global__ __launch_bounds__(256) void init3(const float* __restrict__ state0,
                                             float* __restrict__ stateT,
                                             ushort_t* __restrict__ actF) {
    int idx = blockIdx.x * 256 + threadIdx.x;   // < BB*HH
    int b = idx / HH, h = idx - b * HH;
    float s = state0[idx];
    int r = (h < ESZ) ? ((h >> 9) * 640 + (h & 511))
                      : (((h - ESZ) >> 7) * 640 + 512 + ((h - ESZ) & 127));
    stateT[r * BB + b] = s;
    scatter_act(actF, h, b, f2bf(retanh_f(s)));
}

// ============ one RNN step: bf16 MFMA GEMM ============
// 640 blocks x 256 thr (4 waves). Block = (area, mt_local, nt): 16 rows x 16 batch,
// waves K-split 4. A/B frags are lane-consecutive dwordx4 loads (coalesced).
// bid encode: bit0=ntLow, bits1-2=area, bit3=ntHigh, bits4+=mt_local -> XCD=bid%8
// pins area a to XCD pair {2a,2a+1}: WF area slice 2.1MB + actF 0.2MB < 4MB L2.
__global__ __launch_bounds__(256, 4) void step8(
    const ushort_t* __restrict__ WF,
    const ushort_t* __restrict__ actF_in,
    ushort_t* __restrict__ actF_out,
    const ushort_t* __restrict__ xFt,     // this step's x fragments (area0 cols)
    const float* __restrict__ brec,
    float* __restrict__ stateT,           // [r][BB] fp32
    float* __restrict__ out_t)            // [BB][HH] fp32
{
    __shared__ float part[4 * 256];
    const int tid = threadIdx.x, lane = tid & 63, wv = tid >> 6;
    const int bid = blockIdx.x;
    const int area = (bid >> 1) & 3;
    const int nt   = ((bid >> 2) & 2) | (bid & 1);
    const int ml   = bid >> 4;            // mt_local 0..39
    const int mt   = area * 40 + ml;
    const int r0   = area * 640 + ml * 16;
    const int KC   = area_kc(area);
    const int kcx  = (area == 0) ? 36 : 64;   // kc >= kcx -> x-fragment source

    f32x4 acc = {0.f, 0.f, 0.f, 0.f};
    const ushort_t* aptr = WF + (size_t)mt * 52 * 512 + lane * 8;
    const ushort_t* bbase = actF_in + ((area * 52) * 4 + nt) * 512 + lane * 8;

    for (int kc = wv; kc < KC; kc += 4) {
        u16x8 af = *(const u16x8*)(aptr + (size_t)kc * 512);
        const ushort_t* bp = (kc < kcx) ? (bbase + (size_t)kc * 2048)
                                        : (xFt + ((kc - kcx) * 4 + nt) * 512 + lane * 8);
        u16x8 bf = *(const u16x8*)bp;
        // D[m][n] += A[m][k]*B[k][n]; A row m=lane&15, B col n=lane&15, k=(lane>>4)*8+j
        asm volatile("v_mfma_f32_16x16x32_bf16 %0, %1, %2, %0"
                     : "+v"(acc) : "v"(af), "v"(bf));
    }
    // hazard gap: VALU read of MFMA result needs a few cycles
    asm volatile("s_nop 7\n\ts_nop 7" : "+v"(acc));

    // C/D layout: n = lane&15, m = (lane>>4)*4 + i   [m89-verified]
#pragma unroll
    for (int i = 0; i < 4; i++)
        part[wv * 256 + (lane & 15) * 16 + ((lane >> 4) << 2) + i] = acc[i];
    __syncthreads();

    {   // 256 outputs (16m x 16n), one per thread; mm fastest -> h-consecutive stores
        const int mm = tid & 15, nn = tid >> 4;
        float s = part[nn * 16 + mm] + part[256 + nn * 16 + mm]
                + part[512 + nn * 16 + mm] + part[768 + nn * 16 + mm];
        const int b = nt * 16 + nn;
        const int ridx = ml * 16 + mm;
        const int h = (ridx < 512) ? ((area << 9) + ridx)
                                   : (ESZ + (area << 7) + (ridx - 512));
        const int r = r0 + mm;
        float st = stateT[r * BB + b];
        float ns = st * (1.f - ALPHA_C) + ALPHA_C * (s + brec[h]);
        stateT[r * BB + b] = ns;
        float o = retanh_f(ns);
        out_t[(size_t)b * HH + h] = o;
        scatter_act(actF_out, h, b, f2bf(o));
    }
}

// ============ fallback (tiny ws): R6's raw-W streaming path ============
__device__ __forceinline__ void area_params(int area, int& e_lo, int& n_e,
                                            int& i_lo, int& n_rec, int& n_tot) {
    e_lo = (area > 0 ? area - 1 : 0) << 9;
    int e_hi = ((area < 3 ? area + 1 : 3) + 1) << 9;
    n_e = e_hi - e_lo;
    i_lo = ESZ + (area << 7);
    n_rec = n_e + 128;
    n_tot = n_rec + (area == 0 ? INSZ : 0);
}
__device__ __forceinline__ int row_h(int area, int idx) {
    return (idx < 512) ? ((area << 9) + idx) : (ESZ + (area << 7) + (idx - 512));
}
__global__ __launch_bounds__(256) void init_state2(const float* __restrict__ state0,
                                                   float* __restrict__ stateT,
                                                   float* __restrict__ act0) {
    int idx = blockIdx.x * 256 + threadIdx.x;
    int b = idx / HH, h = idx - b * HH;
    float s = state0[idx];
    int r = (h < ESZ) ? ((h >> 9) * 640 + (h & 511))
                      : (((h - ESZ) >> 7) * 640 + 512 + ((h - ESZ) & 127));
    stateT[r * BB + b] = s;
    act0[((h >> 1) << 7) + b * 2 + (h & 1)] = retanh_f(s);
}
__global__ __launch_bounds__(1024, 4) void step_raw(
    const float* __restrict__ W, const float* __restrict__ Win,
    const float* __restrict__ brec, const float* __restrict__ x_t,
    const float* __restrict__ actIn, float* __restrict__ actOut,
    float* __restrict__ stateT, float* __restrict__ out_t)
{
    __shared__ float part[16 * 680];
    const int tid = threadIdx.x, lane = tid & 63, wv = tid >> 6;
    const int area = blockIdx.x >> 6;
    const int rb = (blockIdx.x & 63) * 10;
    int e_lo, n_e, i_lo, n_rec, n_tot;
    area_params(area, e_lo, n_e, i_lo, n_rec, n_tot);
    const int r0 = area * 640 + rb;
    const int C = n_tot >> 4;
    float2 acc[10];
#pragma unroll
    for (int j = 0; j < 10; j++) acc[j] = make_float2(0.f, 0.f);
    for (int c = wv; c < C; c += 16) {
        const int p0 = c << 4;
        float2 av[8];
        int cbase;
        if (p0 < n_rec) {
            cbase = (p0 < n_e) ? (e_lo + p0) : (i_lo + (p0 - n_e));
            const float* ap = actIn + ((cbase >> 1) << 7) + lane * 2;
#pragma unroll
            for (int i = 0; i < 8; i++) av[i] = *(const float2*)(ap + (i << 7));
        } else {
            cbase = -1;
            const int k0 = p0 - n_rec;
            const float4* xp = (const float4*)(x_t + lane * INSZ + k0);
#pragma unroll
            for (int q = 0; q < 4; q++) {
                float4 v = xp[q];
                av[2 * q]     = make_float2(fmaxf(v.x, 0.f), fmaxf(v.y, 0.f));
                av[2 * q + 1] = make_float2(fmaxf(v.z, 0.f), fmaxf(v.w, 0.f));
            }
        }
#pragma unroll
        for (int j = 0; j < 10; j++) {
            const int h = row_h(area, rb + j);
            const float sgn = (cbase >= 0 && p0 >= n_e) ? -1.f : 1.f;
            const float* wr = (cbase >= 0) ? (W + (size_t)h * HH + cbase)
                                           : (Win + (size_t)h * INSZ + (p0 - n_rec));
#pragma unroll
            for (int i = 0; i < 8; i++) {
                acc[j].x = fmaf(sgn * fabsf(wr[2 * i]),     av[i].x, acc[j].x);
                acc[j].y = fmaf(sgn * fabsf(wr[2 * i + 1]), av[i].y, acc[j].y);
            }
        }
    }
#pragma unroll
    for (int j = 0; j < 10; j++)
        part[wv * 680 + j * 68 + lane] = acc[j].x + acc[j].y;
    __syncthreads();
    int j = -1, b = 0;
    if (tid < 512)      { b = tid >> 3;      j = tid & 7; }
    else if (tid < 640) { int u = tid - 512; b = u >> 1;  j = 8 + (u & 1); }
    if (j >= 0) {
        const int h = row_h(area, rb + j);
        float s = 0.f;
#pragma unroll
        for (int w16 = 0; w16 < 16; w16++) s += part[w16 * 680 + j * 68 + b];
        float sgn = (h < ESZ) ? 1.f : -1.f;
        s -= sgn * fabsf(W[(size_t)h * HH + h]) * actIn[((h >> 1) << 7) + b * 2 + (h & 1)];
        const int r = r0 + j;
        float st = stateT[r * BB + b];
        float ns = st * (1.f - ALPHA_C) + ALPHA_C * (s + brec[h]);
        stateT[r * BB + b] = ns;
        float o = retanh_f(ns);
        out_t[(size_t)b * HH + h] = o;
        actOut[((h >> 1) << 7) + b * 2 + (h & 1)] = o;
    }
}

extern "C" void kernel_launch(void* const* d_in, const int* in_sizes, int n_in,
                              void* d_out, int out_size, void* d_ws, size_t ws_size,
                              hipStream_t stream) {
    const float* x      = (const float*)d_in[0];
    const float* W_in   = (const float*)d_in[1];
    const float* W_rec  = (const float*)d_in[2];
    const float* b_rec  = (const float*)d_in[3];
    const float* state0 = (const float*)d_in[4];
    float* out = (float*)d_out;

    const size_t WFn = (size_t)160 * 52 * 512;   // 4,259,840 bf16
    const size_t xFn = (size_t)TT * 8192;        //   262,144 bf16
    const size_t aFn = (size_t)4 * 52 * 4 * 512; //   425,984 bf16
    const size_t need = (WFn + xFn + 2 * aFn) * 2 + (size_t)HH * BB * 4;

    if (ws_size >= need) {
        ushort_t* WF   = (ushort_t*)d_ws;
        ushort_t* xF   = WF + WFn;
        ushort_t* actA = xF + xFn;
        ushort_t* actB = actA + aFn;
        float* stateT  = (float*)(actB + aFn);

        wf_pack<<<16640, 256, 0, stream>>>(W_rec, W_in, WF);
        xf_pack<<<1024, 256, 0, stream>>>(x, xF);
        init3<<<640, 256, 0, stream>>>(state0, stateT, actA);
        for (int t = 0; t < TT; t++) {
            ushort_t* ai = (t & 1) ? actB : actA;
            ushort_t* ao = (t & 1) ? actA : actB;
            step8<<<640, 256, 0, stream>>>(WF, ai, ao, xF + (size_t)t * 8192,
                                           b_rec, stateT, out + (size_t)t * BB * HH);
        }
    } else {
        float* ws = (float*)d_ws;
        const size_t bufElems = (size_t)HH * BB;
        float* stateT = ws;
        float* actA   = stateT + bufElems;
        float* actB   = actA + bufElems;
        init_state2<<<(BB * HH) / 256, 256, 0, stream>>>(state0, stateT, actA);
        for (int t = 0; t < TT; t++) {
            const float* ai = (t & 1) ? actB : actA;
            float* ao       = (t & 1) ? actA : actB;
            step_raw<<<256, 1024, 0, stream>>>(W_rec, W_in, b_rec,
                                               x + (size_t)t * BB * INSZ,
                                               ai, ao, stateT, out + (size_t)t * BB * HH);
        }
    }
}

// Round 11
// 279.951 us; speedup vs baseline: 2.1607x; 1.0764x over previous
//
#include <hip/hip_runtime.h>
#include <math.h>

// Problem constants (from reference)
#define HH   2560
#define ESZ  2048
#define BB   64
#define TT   32
#define INSZ 128
constexpr float ALPHA_C = 0.2f;   // dt_x / tau_x

typedef unsigned short ushort_t;
typedef __attribute__((ext_vector_type(8))) unsigned short u16x8;  // 8 bf16 = 4 VGPRs
typedef __attribute__((ext_vector_type(4))) float f32x4;           // MFMA acc

__device__ __forceinline__ float retanh_f(float v) { return tanhf(fmaxf(v, 0.f)); }
__device__ __forceinline__ ushort_t f2bf(float f) {   // RNE float->bf16
    unsigned u = __float_as_uint(f);
    return (ushort_t)((u + 0x7fffu + ((u >> 16) & 1u)) >> 16);
}

// Area geometry (kron structure). Rows of area a (E and I) share one sparse col set:
// E-cols of areas [a-1..a+1] (n_e), then I-cols of area a (128), then x-cols (area0).
__device__ __forceinline__ int area_ne(int a)  { return (a == 1 || a == 2) ? 1536 : 1024; }
__device__ __forceinline__ int area_elo(int a) { return (a > 0 ? a - 1 : 0) << 9; }

// ============ fragment-layout packers (once per launch) ============
// WF[(mt*52+kc)*512 + lane*8 + j] = bf16 A-fragment: W row m = mt*16+(lane&15),
// packed col k = kc*32 + (lane>>4)*8 + j  (masked/signed/diag-zeroed |W|, Win appended)
// Vectorized: one thread = one 8-element fragment (float4 x2 in, u16x8 out).
__global__ __launch_bounds__(256) void wf_pack8(const float* __restrict__ Wrec,
                                                const float* __restrict__ Win,
                                                ushort_t* __restrict__ WF) {
    int idx = blockIdx.x * 256 + threadIdx.x;   // < 160*52*64
    int l = idx & 63;
    int t = idx >> 6;                 // mt*52 + kc
    int kc = t % 52, mt = t / 52;
    int area = mt / 40, local = mt - area * 40;
    int ridx = local * 16 + (l & 15);             // within-area packed row 0..639
    int h = (ridx < 512) ? ((area << 9) + ridx) : (ESZ + (area << 7) + (ridx - 512));
    int p0 = kc * 32 + ((l >> 4) << 3);
    int ne = area_ne(area), elo = area_elo(area);
    int nrec = ne + 128;
    int ntot = nrec + (area == 0 ? 128 : 0);
    u16x8 o;
#pragma unroll
    for (int j = 0; j < 8; j++) {
        int p = p0 + j;
        float w = 0.f;
        if (p < ne)        { int c = elo + p;                      w = (c == h) ? 0.f :  fabsf(Wrec[(size_t)h * HH + c]); }
        else if (p < nrec) { int c = ESZ + (area << 7) + (p - ne); w = (c == h) ? 0.f : -fabsf(Wrec[(size_t)h * HH + c]); }
        else if (p < ntot) { w = fabsf(Win[(size_t)h * INSZ + (p - nrec)]); }
        o[j] = f2bf(w);
    }
    *(u16x8*)(WF + ((size_t)t * 512 + l * 8)) = o;
}

// xF[t*8192 + kc*2048 + nt*512 + lane*8 + j] = bf16 B-fragment of relu(x_t) for
// area0 x-cols: b = nt*16+(lane&15), k_in = kc*32+(lane>>4)*8+j
__global__ __launch_bounds__(256) void xf_pack(const float* __restrict__ x,
                                               ushort_t* __restrict__ xF) {
    int idx = blockIdx.x * 256 + threadIdx.x;   // < 32*4*4*512
    int j = idx & 7, l = (idx >> 3) & 63;
    int nt = (idx >> 9) & 3, kc = (idx >> 11) & 3, t = idx >> 13;
    int b = nt * 16 + (l & 15);
    int k = kc * 32 + ((l >> 4) << 3) + j;
    xF[idx] = f2bf(fmaxf(x[((size_t)t * BB + b) * INSZ + k], 0.f));
}

// scatter one act value into B-fragment slots of every area whose col-space has h
__device__ __forceinline__ void act_store(ushort_t* actF, int a, int p, int b, ushort_t v) {
    int kc = p >> 5, kk = p & 31;
    int lane = ((kk >> 3) << 4) + (b & 15);
    actF[(((a * 52 + kc) << 2) + (b >> 4)) * 512 + lane * 8 + (kk & 7)] = v;
}
__device__ __forceinline__ void scatter_act(ushort_t* actF, int h, int b, ushort_t v) {
    if (h < ESZ) {
        int ae = h >> 9;
        int alo = ae > 0 ? ae - 1 : 0, ahi = ae < 3 ? ae + 1 : 3;
        for (int a = alo; a <= ahi; a++) act_store(actF, a, h - area_elo(a), b, v);
    } else {
        int ai = (h - ESZ) >> 7;
        act_store(actF, ai, area_ne(ai) + (h - (ESZ + (ai << 7))), b, v);
    }
}

// state0 -> stateT (packed-row fp32) + initial act fragments
__global__ __launch_bounds__(256) void init3(const float* __restrict__ state0,
                                             float* __restrict__ stateT,
                                             ushort_t* __restrict__ actF) {
    int idx = blockIdx.x * 256 + threadIdx.x;   // < BB*HH
    int b = idx / HH, h = idx - b * HH;
    float s = state0[idx];
    int r = (h < ESZ) ? ((h >> 9) * 640 + (h & 511))
                      : (((h - ESZ) >> 7) * 640 + 512 + ((h - ESZ) & 127));
    stateT[r * BB + b] = s;
    scatter_act(actF, h, b, f2bf(retanh_f(s)));
}

// ============ one RNN step: bf16 MFMA GEMM, fully-unrolled K ============
// 640 blocks x 256 thr (4 waves). Block = (area, mt_local, nt): 16 rows x 16 batch,
// waves K-split 4. Compile-time trip counts per area -> ALL af/bf loads issued
// upfront (<=26 dwordx4 in flight), collapsing 13 serial L2/L3 miss latencies
// (cross-XCD actF) into ~1. bid encode: XCD=bid%8 pins area a to XCD pair {2a,2a+1}.
__global__ __launch_bounds__(256) void step9(
    const ushort_t* __restrict__ WF,
    const ushort_t* __restrict__ actF_in,
    ushort_t* __restrict__ actF_out,
    const ushort_t* __restrict__ xFt,     // this step's x fragments (area0 cols)
    const float* __restrict__ brec,
    float* __restrict__ stateT,           // [r][BB] fp32
    float* __restrict__ out_t)            // [BB][HH] fp32
{
    __shared__ float part[4 * 256];
    const int tid = threadIdx.x, lane = tid & 63, wv = tid >> 6;
    const int bid = blockIdx.x;
    const int area = (bid >> 1) & 3;
    const int nt   = ((bid >> 2) & 2) | (bid & 1);
    const int ml   = bid >> 4;            // mt_local 0..39
    const int mt   = area * 40 + ml;
    const int r0   = area * 640 + ml * 16;

    f32x4 acc = {0.f, 0.f, 0.f, 0.f};
    // kc = wv + 4*i ; af offset = kc*512 ; bf offset = ((area*52+kc)*4+nt)*512
    const ushort_t* aptr = WF + ((size_t)mt * 52 + wv) * 512 + lane * 8;
    const ushort_t* bptr = actF_in + (((size_t)area * 52 + wv) * 4 + nt) * 512 + lane * 8;
    const ushort_t* xptr = xFt + ((wv * 4) + nt) * 512 + lane * 8;   // area0, kc=36+wv

#define KLOOP(NIT, HASX)                                                     \
    {                                                                        \
        u16x8 af[NIT], bf[NIT];                                              \
        _Pragma("unroll")                                                    \
        for (int i = 0; i < (NIT); i++) {                                    \
            af[i] = *(const u16x8*)(aptr + (size_t)i * 2048);                \
            bf[i] = ((HASX) && i == (NIT) - 1)                               \
                        ? *(const u16x8*)xptr                                \
                        : *(const u16x8*)(bptr + (size_t)i * 8192);          \
        }                                                                    \
        _Pragma("unroll")                                                    \
        for (int i = 0; i < (NIT); i++)                                      \
            asm volatile("v_mfma_f32_16x16x32_bf16 %0, %1, %2, %0"           \
                         : "+v"(acc) : "v"(af[i]), "v"(bf[i]));              \
    }

    // KC per area: 40 / 52 / 52 / 36 (all %4==0); per-wave NIT = KC/4.
    // Area0: kc in [36,40) are x-chunks -> each wave's LAST iteration.
    if (area == 0)      KLOOP(10, true)
    else if (area == 3) KLOOP(9,  false)
    else                KLOOP(13, false)
#undef KLOOP

    // hazard gap: VALU read of MFMA result needs a few cycles
    asm volatile("s_nop 7\n\ts_nop 7" : "+v"(acc));

    // C/D layout: n = lane&15, m = (lane>>4)*4 + i   [m89-verified]
#pragma unroll
    for (int i = 0; i < 4; i++)
        part[wv * 256 + (lane & 15) * 16 + ((lane >> 4) << 2) + i] = acc[i];
    __syncthreads();

    {   // 256 outputs (16m x 16n), one per thread; mm fastest -> h-consecutive stores
        const int mm = tid & 15, nn = tid >> 4;
        float s = part[nn * 16 + mm] + part[256 + nn * 16 + mm]
                + part[512 + nn * 16 + mm] + part[768 + nn * 16 + mm];
        const int b = nt * 16 + nn;
        const int ridx = ml * 16 + mm;
        const int h = (ridx < 512) ? ((area << 9) + ridx)
                                   : (ESZ + (area << 7) + (ridx - 512));
        const int r = r0 + mm;
        float st = stateT[r * BB + b];
        float ns = st * (1.f - ALPHA_C) + ALPHA_C * (s + brec[h]);
        stateT[r * BB + b] = ns;
        float o = retanh_f(ns);
        out_t[(size_t)b * HH + h] = o;
        scatter_act(actF_out, h, b, f2bf(o));
    }
}

// ============ fallback (tiny ws): R6's raw-W streaming path ============
__device__ __forceinline__ void area_params(int area, int& e_lo, int& n_e,
                                            int& i_lo, int& n_rec, int& n_tot) {
    e_lo = (area > 0 ? area - 1 : 0) << 9;
    int e_hi = ((area < 3 ? area + 1 : 3) + 1) << 9;
    n_e = e_hi - e_lo;
    i_lo = ESZ + (area << 7);
    n_rec = n_e + 128;
    n_tot = n_rec + (area == 0 ? INSZ : 0);
}
__device__ __forceinline__ int row_h(int area, int idx) {
    return (idx < 512) ? ((area << 9) + idx) : (ESZ + (area << 7) + (idx - 512));
}
__global__ __launch_bounds__(256) void init_state2(const float* __restrict__ state0,
                                                   float* __restrict__ stateT,
                                                   float* __restrict__ act0) {
    int idx = blockIdx.x * 256 + threadIdx.x;
    int b = idx / HH, h = idx - b * HH;
    float s = state0[idx];
    int r = (h < ESZ) ? ((h >> 9) * 640 + (h & 511))
                      : (((h - ESZ) >> 7) * 640 + 512 + ((h - ESZ) & 127));
    stateT[r * BB + b] = s;
    act0[((h >> 1) << 7) + b * 2 + (h & 1)] = retanh_f(s);
}
__global__ __launch_bounds__(1024, 4) void step_raw(
    const float* __restrict__ W, const float* __restrict__ Win,
    const float* __restrict__ brec, const float* __restrict__ x_t,
    const float* __restrict__ actIn, float* __restrict__ actOut,
    float* __restrict__ stateT, float* __restrict__ out_t)
{
    __shared__ float part[16 * 680];
    const int tid = threadIdx.x, lane = tid & 63, wv = tid >> 6;
    const int area = blockIdx.x >> 6;
    const int rb = (blockIdx.x & 63) * 10;
    int e_lo, n_e, i_lo, n_rec, n_tot;
    area_params(area, e_lo, n_e, i_lo, n_rec, n_tot);
    const int r0 = area * 640 + rb;
    const int C = n_tot >> 4;
    float2 acc[10];
#pragma unroll
    for (int j = 0; j < 10; j++) acc[j] = make_float2(0.f, 0.f);
    for (int c = wv; c < C; c += 16) {
        const int p0 = c << 4;
        float2 av[8];
        int cbase;
        if (p0 < n_rec) {
            cbase = (p0 < n_e) ? (e_lo + p0) : (i_lo + (p0 - n_e));
            const float* ap = actIn + ((cbase >> 1) << 7) + lane * 2;
#pragma unroll
            for (int i = 0; i < 8; i++) av[i] = *(const float2*)(ap + (i << 7));
        } else {
            cbase = -1;
            const int k0 = p0 - n_rec;
            const float4* xp = (const float4*)(x_t + lane * INSZ + k0);
#pragma unroll
            for (int q = 0; q < 4; q++) {
                float4 v = xp[q];
                av[2 * q]     = make_float2(fmaxf(v.x, 0.f), fmaxf(v.y, 0.f));
                av[2 * q + 1] = make_float2(fmaxf(v.z, 0.f), fmaxf(v.w, 0.f));
            }
        }
#pragma unroll
        for (int j = 0; j < 10; j++) {
            const int h = row_h(area, rb + j);
            const float sgn = (cbase >= 0 && p0 >= n_e) ? -1.f : 1.f;
            const float* wr = (cbase >= 0) ? (W + (size_t)h * HH + cbase)
                                           : (Win + (size_t)h * INSZ + (p0 - n_rec));
#pragma unroll
            for (int i = 0; i < 8; i++) {
                acc[j].x = fmaf(sgn * fabsf(wr[2 * i]),     av[i].x, acc[j].x);
                acc[j].y = fmaf(sgn * fabsf(wr[2 * i + 1]), av[i].y, acc[j].y);
            }
        }
    }
#pragma unroll
    for (int j = 0; j < 10; j++)
        part[wv * 680 + j * 68 + lane] = acc[j].x + acc[j].y;
    __syncthreads();
    int j = -1, b = 0;
    if (tid < 512)      { b = tid >> 3;      j = tid & 7; }
    else if (tid < 640) { int u = tid - 512; b = u >> 1;  j = 8 + (u & 1); }
    if (j >= 0) {
        const int h = row_h(area, rb + j);
        float s = 0.f;
#pragma unroll
        for (int w16 = 0; w16 < 16; w16++) s += part[w16 * 680 + j * 68 + b];
        float sgn = (h < ESZ) ? 1.f : -1.f;
        s -= sgn * fabsf(W[(size_t)h * HH + h]) * actIn[((h >> 1) << 7) + b * 2 + (h & 1)];
        const int r = r0 + j;
        float st = stateT[r * BB + b];
        float ns = st * (1.f - ALPHA_C) + ALPHA_C * (s + brec[h]);
        stateT[r * BB + b] = ns;
        float o = retanh_f(ns);
        out_t[(size_t)b * HH + h] = o;
        actOut[((h >> 1) << 7) + b * 2 + (h & 1)] = o;
    }
}

extern "C" void kernel_launch(void* const* d_in, const int* in_sizes, int n_in,
                              void* d_out, int out_size, void* d_ws, size_t ws_size,
                              hipStream_t stream) {
    const float* x      = (const float*)d_in[0];
    const float* W_in   = (const float*)d_in[1];
    const float* W_rec  = (const float*)d_in[2];
    const float* b_rec  = (const float*)d_in[3];
    const float* state0 = (const float*)d_in[4];
    float* out = (float*)d_out;

    const size_t WFn = (size_t)160 * 52 * 512;   // 4,259,840 bf16
    const size_t xFn = (size_t)TT * 8192;        //   262,144 bf16
    const size_t aFn = (size_t)4 * 52 * 4 * 512; //   425,984 bf16
    const size_t need = (WFn + xFn + 2 * aFn) * 2 + (size_t)HH * BB * 4;

    if (ws_size >= need) {
        ushort_t* WF   = (ushort_t*)d_ws;
        ushort_t* xF   = WF + WFn;
        ushort_t* actA = xF + xFn;
        ushort_t* actB = actA + aFn;
        float* stateT  = (float*)(actB + aFn);

        wf_pack8<<<2080, 256, 0, stream>>>(W_rec, W_in, WF);
        xf_pack<<<1024, 256, 0, stream>>>(x, xF);
        init3<<<640, 256, 0, stream>>>(state0, stateT, actA);
        for (int t = 0; t < TT; t++) {
            ushort_t* ai = (t & 1) ? actB : actA;
            ushort_t* ao = (t & 1) ? actA : actB;
            step9<<<640, 256, 0, stream>>>(WF, ai, ao, xF + (size_t)t * 8192,
                                           b_rec, stateT, out + (size_t)t * BB * HH);
        }
    } else {
        float* ws = (float*)d_ws;
        const size_t bufElems = (size_t)HH * BB;
        float* stateT = ws;
        float* actA   = stateT + bufElems;
        float* actB   = actA + bufElems;
        init_state2<<<(BB * HH) / 256, 256, 0, stream>>>(state0, stateT, actA);
        for (int t = 0; t < TT; t++) {
            const float* ai = (t & 1) ? actB : actA;
            float* ao       = (t & 1) ? actA : actB;
            step_raw<<<256, 1024, 0, stream>>>(W_rec, W_in, b_rec,
                                               x + (size_t)t * BB * INSZ,
                                               ai, ao, stateT, out + (size_t)t * BB * HH);
        }
    }
}